// Round 6
// baseline (18703.690 us; speedup 1.0000x reference)
//
// TrajectoryPredictor: 2-layer GRU enc (50 steps) -> autoregressive 2-layer GRU dec (30 steps) + fc head.
// Strategy: fp16 MFMA (16x16x32_f16) GEMM per layer-step, gate math fused in epilogue; state fp16 ping-pong.
// R2: LDS granule swizzle -> conflicts 0.   R3/R5: XCD-aware block swizzle.
// R7: BM=128 mt2, 3blk/CU: 127us L1, Mfma 36.  R8: BM=256 mt4, 2blk/CU: 119us, Mfma 38 (BEST).
// R9 FAILED: depth-1 prefetch + drain-0 (153us).  R10 FAILED: BK=32 ring, barrier/VALU bloat (168us).
// R11 FAILED: A-in-regs broke write merging (WRITE 102MB).  R12 FAILED: (256,3) forced spill
//     (VGPR 84, WRITE 200MB scratch traffic, 151us). LESSON: mt4 caps at 2 waves/SIMD.
// All 2-phase variants pin at ~38% MfmaUtil -> regime gate. R13 (this): faithful counted-vmcnt
//     phase pipeline: 512thr/8 waves, BM=256 (mt2 nt2, 64 acc/wave -> no spill), BN=32 (write
//     pattern byte-identical to R8), ring of 3 LDS slots (3x44KB=132KB, 1 blk/CU), lookahead-2.
//     Per kc: 2 phases {8 ds_read -> stage-issue -> barrier -> 12 MFMA (setprio)}; single counted
//     wait per kc: vmcnt(7) [waves 0-3: 4A+3B loads/kc] / vmcnt(4) [waves 4-7: 4A], NEVER drain-0
//     in the loop. sched_barrier(0) pins after every s_barrier.
// ws ~137 MB: 4x fp16 state (128MB) + packed weights (9MB) + biases.
#include <hip/hip_runtime.h>
#include <hip/hip_fp16.h>
#include <stdint.h>

typedef _Float16 h8 __attribute__((ext_vector_type(8)));
typedef float f4 __attribute__((ext_vector_type(4)));

#define DEV static __device__ __forceinline__

constexpr int BATCH  = 32768;
constexpr int HID    = 512;
constexpr int T_HIST = 50;
constexpr int FUT    = 30;
constexpr int BM = 256, BN = 32, BK = 64;
constexpr int SLOT = BM * BK + 3 * BN * BK;   // 16384 + 6144 = 22528 halfs (44KB) per ring slot

DEV void gl2lds16(const void* g, void* l) {
  __builtin_amdgcn_global_load_lds(
      (const __attribute__((address_space(1))) void*)g,
      (__attribute__((address_space(3))) void*)l,
      16, 0, 0);
}

DEV float sigm(float x)     { return 1.f / (1.f + __expf(-x)); }
DEV float tanhfast(float x) { return 1.f - 2.f / (__expf(2.f * x) + 1.f); }

// ---------------- utility: zero fill (graph-safe) ----------------
__global__ void zero_fill(float4* __restrict__ p, int n4) {
  int i = blockIdx.x * 256 + threadIdx.x;
  if (i < n4) p[i] = float4{0.f, 0.f, 0.f, 0.f};
}

// ---------------- weight/bias repack kernels ----------------
// target layout: (((nb*KC + kc)*3 + g)*32 + n)*64 + k, 16 col-blocks of 32 n, with 16B-granule
// XOR swizzle: stored granule k8s holds logical k8 = k8s ^ (n&7). source row = g*512 + nb*32 + n.
__global__ void pack_w(const float* __restrict__ Wa, const float* __restrict__ Wb,
                       _Float16* __restrict__ out, int KC) {
  int i = blockIdx.x * 256 + threadIdx.x;
  int total = 16 * KC * 3 * 32 * 64;
  if (i >= total) return;
  int k0  = i & 7;          // element within 16B granule
  int k8s = (i >> 3) & 7;   // stored granule index
  int n   = (i >> 6) & 31;
  int t   = i >> 11;        // (nb*KC + kc)*3 + g
  int g   = t % 3;
  int t2  = t / 3;
  int kc  = t2 % KC;
  int nb  = t2 / KC;
  int k8  = k8s ^ (n & 7);  // logical granule
  int row = g * 512 + nb * 32 + n;
  int kg  = kc * 64 + k8 * 8 + k0;
  float v = (kg < 512) ? Wa[(size_t)row * 512 + kg] : Wb[(size_t)row * 512 + kg - 512];
  out[i] = (_Float16)v;
}

// bias combine: [0]=b_ih_r+b_hh_r, [1]=b_ih_z+b_hh_z, [2]=b_ih_n, [3]=b_hh_n  (each 512)
__global__ void pack_bias(const float* __restrict__ bih, const float* __restrict__ bhh,
                          float* __restrict__ out) {
  int j = blockIdx.x * 256 + threadIdx.x;
  if (j >= 512) return;
  out[j]        = bih[j]        + bhh[j];
  out[512 + j]  = bih[512 + j]  + bhh[512 + j];
  out[1024 + j] = bih[1024 + j];
  out[1536 + j] = bhh[1024 + j];
}

// x-weights for layer0 (K=3): out[j*9 + g*3 + k] = W_ih[(g*512+j)*3 + k]
__global__ void pack_wx(const float* __restrict__ Wih, float* __restrict__ out) {
  int i = blockIdx.x * 256 + threadIdx.x;
  if (i >= 512 * 9) return;
  int j = i / 9, q = i % 9, g = q / 3, k = q % 3;
  out[i] = Wih[(size_t)(g * 512 + j) * 3 + k];
}

// ---------------- fused GRU layer-step GEMM, counted-vmcnt phase pipeline ----------------
// Block: 512 thr / 8 waves; wave w rows w*32..w*32+31, all 32 cols (mt2 x nt2, 64 acc f32).
// Ring of 3 LDS slots, lookahead-2: during kc s, stage(s+2) is issued (A at phase 0, B at phase 1);
// end-of-kc counted wait confirms kc s+1's loads (issued one kc earlier) while keeping this kc's
// issues in flight. Phases: {8 ds_read_b128; stage-issue; s_barrier; 12 MFMA in setprio}.
// Staging split: all 8 waves issue 4 A-granule-loads/kc; waves 0-3 additionally 3 B-loads/kc.
// Grid: flat 2048; XCD-aware remap (16 col-blocks of a row-block on one XCD, adjacent in time).
template <int KC, bool L0>
__launch_bounds__(512, 2)
__global__ void gru_step(const _Float16* __restrict__ Bp,     // packed weights [16][KC][3][32][64] (swizzled)
                         const _Float16* __restrict__ Alo,    // fp16 A, k<512 (L0: old state; L1: layer0 out)
                         const _Float16* __restrict__ Ahi,    // fp16 A, k>=512 (L1: old state)
                         _Float16* __restrict__ hnew16,       // fp16 new state
                         const float* __restrict__ bias,      // [4*512]
                         const float* __restrict__ Wx,        // [512*9] (L0) or null
                         const float* __restrict__ xin,       // x row base (L0) or null
                         int xstride) {
  __shared__ alignas(16) _Float16 lds[3 * SLOT];   // 132KB: 3 x {A 256x64 | B 3x32x64}

  const int tid  = threadIdx.x;
  const int wave = tid >> 6;        // 0..7
  const int lane = tid & 63;
  const int quad = lane >> 4;
  const int l15  = lane & 15;
  const int L  = blockIdx.x;              // 0..2047
  const int c  = L & 7;
  const int q  = L >> 3;                  // 0..255
  const int cb = q & 15;                  // 0..15
  const int rb = (c << 4) | (q >> 4);     // 0..127
  const int row0 = rb * BM;
  const int col0 = cb * BN;

  f4 acc_r[2][2]  = {};
  f4 acc_z[2][2]  = {};
  f4 acc_n0[2][2] = {};   // L1: i_n (kc<8); L0 unused (DCE'd)
  f4 acc_n1[2][2] = {};   // h_n

  const _Float16* Bblk = Bp + (size_t)cb * KC * (3 * BN * BK);

  // A-staging: every wave issues 4 gl2lds per kc (2048 granules total)
  auto stageA = [&](int kcs, int slot) {
    const _Float16* Asrc = (KC == 16 && kcs >= 8) ? Ahi : Alo;
    const int kb = (kcs & 7) * BK;
    _Float16* base = &lds[slot * SLOT];
#pragma unroll
    for (int i = 0; i < 4; ++i) {
      int ga = wave * 256 + i * 64 + lane;   // granule = m*8 + k8s
      int m = ga >> 3, k8s = ga & 7;
      int k8l = k8s ^ (m & 7);
      gl2lds16(Asrc + (size_t)(row0 + m) * HID + kb + k8l * 8,
               base + (size_t)(wave * 256 + i * 64) * 8);   // HW adds lane*16B
    }
  };
  // B-staging: waves 0-3 issue 3 gl2lds per kc (768 granules; swizzle pre-baked by pack_w)
  auto stageB = [&](int kcs, int slot) {
    const _Float16* Bsrc = Bblk + (size_t)kcs * (3 * BN * BK);
    _Float16* base = &lds[slot * SLOT] + BM * BK;
#pragma unroll
    for (int i = 0; i < 3; ++i) {
      int gb = wave * 192 + i * 64;
      gl2lds16(Bsrc + (size_t)(gb + lane) * 8, base + (size_t)gb * 8);
    }
  };

  // prologue: fill slots 0 and 1; counted wait (slot 0 landed, slot 1 in flight)
  stageA(0, 0); if (wave < 4) stageB(0, 0);
  stageA(1, 1); if (wave < 4) stageB(1, 1);
  if (wave < 4) asm volatile("s_waitcnt vmcnt(7)" ::: "memory");
  else          asm volatile("s_waitcnt vmcnt(4)" ::: "memory");
  __builtin_amdgcn_s_barrier();
  __builtin_amdgcn_sched_barrier(0);

  int cur = 0, nx2 = 2;
  for (int s = 0; s < KC; ++s) {
    const _Float16* sAc = &lds[cur * SLOT];
    const _Float16* sBc = sAc + BM * BK;
#pragma unroll
    for (int sh = 0; sh < 2; ++sh) {
      // ---- phase sh: ds_read subtile + stage-issue, barrier, MFMA cluster ----
      const int sw = ((sh * 4 + quad) ^ (l15 & 7)) * 8;
      h8 af0 = *(const h8*)&sAc[(wave * 32 + 0 * 16 + l15) * BK + sw];
      h8 af1 = *(const h8*)&sAc[(wave * 32 + 1 * 16 + l15) * BK + sw];
      h8 br0 = *(const h8*)&sBc[(0 * BN + 0 * 16 + l15) * BK + sw];
      h8 bz0 = *(const h8*)&sBc[(1 * BN + 0 * 16 + l15) * BK + sw];
      h8 bn0 = *(const h8*)&sBc[(2 * BN + 0 * 16 + l15) * BK + sw];
      h8 br1 = *(const h8*)&sBc[(0 * BN + 1 * 16 + l15) * BK + sw];
      h8 bz1 = *(const h8*)&sBc[(1 * BN + 1 * 16 + l15) * BK + sw];
      h8 bn1 = *(const h8*)&sBc[(2 * BN + 1 * 16 + l15) * BK + sw];
      if (s + 2 < KC) {
        if (sh == 0) stageA(s + 2, nx2);            // A-issue at phase 0
        else if (wave < 4) stageB(s + 2, nx2);      // B-issue at phase 1
      }
      __builtin_amdgcn_s_barrier();
      __builtin_amdgcn_sched_barrier(0);
      __builtin_amdgcn_s_setprio(1);
      acc_r[0][0] = __builtin_amdgcn_mfma_f32_16x16x32_f16(af0, br0, acc_r[0][0], 0, 0, 0);
      acc_r[1][0] = __builtin_amdgcn_mfma_f32_16x16x32_f16(af1, br0, acc_r[1][0], 0, 0, 0);
      acc_r[0][1] = __builtin_amdgcn_mfma_f32_16x16x32_f16(af0, br1, acc_r[0][1], 0, 0, 0);
      acc_r[1][1] = __builtin_amdgcn_mfma_f32_16x16x32_f16(af1, br1, acc_r[1][1], 0, 0, 0);
      acc_z[0][0] = __builtin_amdgcn_mfma_f32_16x16x32_f16(af0, bz0, acc_z[0][0], 0, 0, 0);
      acc_z[1][0] = __builtin_amdgcn_mfma_f32_16x16x32_f16(af1, bz0, acc_z[1][0], 0, 0, 0);
      acc_z[0][1] = __builtin_amdgcn_mfma_f32_16x16x32_f16(af0, bz1, acc_z[0][1], 0, 0, 0);
      acc_z[1][1] = __builtin_amdgcn_mfma_f32_16x16x32_f16(af1, bz1, acc_z[1][1], 0, 0, 0);
      if (L0 || s >= 8) {
        acc_n1[0][0] = __builtin_amdgcn_mfma_f32_16x16x32_f16(af0, bn0, acc_n1[0][0], 0, 0, 0);
        acc_n1[1][0] = __builtin_amdgcn_mfma_f32_16x16x32_f16(af1, bn0, acc_n1[1][0], 0, 0, 0);
        acc_n1[0][1] = __builtin_amdgcn_mfma_f32_16x16x32_f16(af0, bn1, acc_n1[0][1], 0, 0, 0);
        acc_n1[1][1] = __builtin_amdgcn_mfma_f32_16x16x32_f16(af1, bn1, acc_n1[1][1], 0, 0, 0);
      } else {
        acc_n0[0][0] = __builtin_amdgcn_mfma_f32_16x16x32_f16(af0, bn0, acc_n0[0][0], 0, 0, 0);
        acc_n0[1][0] = __builtin_amdgcn_mfma_f32_16x16x32_f16(af1, bn0, acc_n0[1][0], 0, 0, 0);
        acc_n0[0][1] = __builtin_amdgcn_mfma_f32_16x16x32_f16(af0, bn1, acc_n0[0][1], 0, 0, 0);
        acc_n0[1][1] = __builtin_amdgcn_mfma_f32_16x16x32_f16(af1, bn1, acc_n0[1][1], 0, 0, 0);
      }
      __builtin_amdgcn_s_setprio(0);
      // end-of-kc counted wait (before the closing barrier): confirms kc s+1's loads (issued
      // one kc ago) have landed; keeps this kc's stage(s+2) issues in flight. Never drains fresh.
      if (sh == 1 && s + 1 < KC) {
        if (s + 2 < KC) {
          if (wave < 4) asm volatile("s_waitcnt vmcnt(7)" ::: "memory");
          else          asm volatile("s_waitcnt vmcnt(4)" ::: "memory");
        } else {
          asm volatile("s_waitcnt vmcnt(0)" ::: "memory");  // tail: loads are ~2 kc old, free
        }
      }
      __builtin_amdgcn_sched_barrier(0);
      __builtin_amdgcn_s_barrier();
      __builtin_amdgcn_sched_barrier(0);
    }
    cur = (cur == 2) ? 0 : cur + 1;
    nx2 = (nx2 == 2) ? 0 : nx2 + 1;
  }

  // ---------------- fused epilogue: gates + state update ----------------
  const _Float16* hold16 = L0 ? Alo : Ahi;
  float bR[2], bZ[2], bI[2], bH[2];
  float wx[2][9];
#pragma unroll
  for (int nt = 0; nt < 2; ++nt) {
    int j = col0 + nt * 16 + l15;
    bR[nt] = bias[j];
    bZ[nt] = bias[512 + j];
    bI[nt] = bias[1024 + j];
    bH[nt] = bias[1536 + j];
    if constexpr (L0) {
#pragma unroll
      for (int q2 = 0; q2 < 9; ++q2) wx[nt][q2] = Wx[j * 9 + q2];
    }
  }
  float xv[2][4][3];
  if constexpr (L0) {
#pragma unroll
    for (int mt = 0; mt < 2; ++mt)
#pragma unroll
      for (int r = 0; r < 4; ++r) {
        int b = row0 + wave * 32 + mt * 16 + quad * 4 + r;
        const float* xp = xin + (size_t)b * xstride;
        xv[mt][r][0] = xp[0]; xv[mt][r][1] = xp[1]; xv[mt][r][2] = xp[2];
      }
  }
#pragma unroll
  for (int mt = 0; mt < 2; ++mt) {
#pragma unroll
    for (int r = 0; r < 4; ++r) {
      int b = row0 + wave * 32 + mt * 16 + quad * 4 + r;   // C/D: row = quad*4+reg
#pragma unroll
      for (int nt = 0; nt < 2; ++nt) {
        int j = col0 + nt * 16 + l15;                       // C/D: col = lane&15
        size_t idx = (size_t)b * HID + j;
        float rr = acc_r[mt][nt][r] + bR[nt];
        float zz = acc_z[mt][nt][r] + bZ[nt];
        float hn = acc_n1[mt][nt][r] + bH[nt];
        float in_;
        if constexpr (L0) {
          const float* w = wx[nt];
          rr += xv[mt][r][0] * w[0] + xv[mt][r][1] * w[1] + xv[mt][r][2] * w[2];
          zz += xv[mt][r][0] * w[3] + xv[mt][r][1] * w[4] + xv[mt][r][2] * w[5];
          in_ = bI[nt] + xv[mt][r][0] * w[6] + xv[mt][r][1] * w[7] + xv[mt][r][2] * w[8];
        } else {
          in_ = acc_n0[mt][nt][r] + bI[nt];
        }
        float rg = sigm(rr);
        float zg = sigm(zz);
        float ng = tanhfast(in_ + rg * hn);
        float hp = (float)hold16[idx];
        float hv = (1.f - zg) * ng + zg * hp;
        hnew16[idx] = (_Float16)hv;
      }
    }
  }
}

// ---------------- fc head: pred[b,d] = h[b,:] . fcW[d,:] + fcb[d] ----------------
__global__ __launch_bounds__(256) void fc_kernel(const _Float16* __restrict__ h,
                                                 const float* __restrict__ W,
                                                 const float* __restrict__ bfc,
                                                 float* __restrict__ out) {  // out = d_out + t*3
  int wave = threadIdx.x >> 6, lane = threadIdx.x & 63;
  int b = blockIdx.x * 4 + wave;
  const h8* hp = (const h8*)(h + (size_t)b * 512);
  h8 a0 = hp[lane];
  float s[3];
#pragma unroll
  for (int d = 0; d < 3; ++d) {
    const float4* wp = (const float4*)(W + d * 512);
    float4 w0 = wp[lane * 2], w1 = wp[lane * 2 + 1];
    s[d] = (float)a0[0] * w0.x + (float)a0[1] * w0.y + (float)a0[2] * w0.z + (float)a0[3] * w0.w
         + (float)a0[4] * w1.x + (float)a0[5] * w1.y + (float)a0[6] * w1.z + (float)a0[7] * w1.w;
  }
#pragma unroll
  for (int d = 0; d < 3; ++d)
#pragma unroll
    for (int off = 32; off > 0; off >>= 1) s[d] += __shfl_xor(s[d], off, 64);
  if (lane == 0) {
    out[(size_t)b * 90 + 0] = s[0] + bfc[0];
    out[(size_t)b * 90 + 1] = s[1] + bfc[1];
    out[(size_t)b * 90 + 2] = s[2] + bfc[2];
  }
}

extern "C" void kernel_launch(void* const* d_in, const int* in_sizes, int n_in,
                              void* d_out, int out_size, void* d_ws, size_t ws_size,
                              hipStream_t stream) {
  (void)in_sizes; (void)n_in; (void)out_size; (void)ws_size;
  const float* x_input = (const float*)d_in[0];
  const float* eWih0 = (const float*)d_in[2];
  const float* eWhh0 = (const float*)d_in[3];
  const float* ebih0 = (const float*)d_in[4];
  const float* ebhh0 = (const float*)d_in[5];
  const float* eWih1 = (const float*)d_in[6];
  const float* eWhh1 = (const float*)d_in[7];
  const float* ebih1 = (const float*)d_in[8];
  const float* ebhh1 = (const float*)d_in[9];
  const float* dWih0 = (const float*)d_in[10];
  const float* dWhh0 = (const float*)d_in[11];
  const float* dbih0 = (const float*)d_in[12];
  const float* dbhh0 = (const float*)d_in[13];
  const float* dWih1 = (const float*)d_in[14];
  const float* dWhh1 = (const float*)d_in[15];
  const float* dbih1 = (const float*)d_in[16];
  const float* dbhh1 = (const float*)d_in[17];
  const float* fcW   = (const float*)d_in[18];
  const float* fcb   = (const float*)d_in[19];
  float* out = (float*)d_out;

  char* ws = (char*)d_ws;
  const size_t S16 = (size_t)BATCH * HID * 2;   // 32MB
  _Float16* h0h[2] = {(_Float16*)(ws),            (_Float16*)(ws + S16)};
  _Float16* h1h[2] = {(_Float16*)(ws + 2 * S16),  (_Float16*)(ws + 3 * S16)};
  char* p = ws + 4 * S16;                        // 128MB
  const size_t W8  = (size_t)16 * 8  * 3 * 32 * 64 * 2;  // 1.5MB (KC=8)
  const size_t W16 = (size_t)16 * 16 * 3 * 32 * 64 * 2;  // 3MB (KC=16)
  _Float16* pkE0 = (_Float16*)p; p += W8;
  _Float16* pkE1 = (_Float16*)p; p += W16;
  _Float16* pkD0 = (_Float16*)p; p += W8;
  _Float16* pkD1 = (_Float16*)p; p += W16;
  float* bE0 = (float*)p; p += 2048 * 4;
  float* bE1 = (float*)p; p += 2048 * 4;
  float* bD0 = (float*)p; p += 2048 * 4;
  float* bD1 = (float*)p; p += 2048 * 4;
  float* wxE = (float*)p; p += 512 * 9 * 4;
  float* wxD = (float*)p; p += 512 * 9 * 4;
  // total ws usage: 128MB + ~9.1MB

  // repack weights/biases (every call; ws is re-poisoned by harness)
  pack_w<<<dim3(3072), 256, 0, stream>>>(eWhh0, eWhh0, pkE0, 8);
  pack_w<<<dim3(6144), 256, 0, stream>>>(eWih1, eWhh1, pkE1, 16);
  pack_w<<<dim3(3072), 256, 0, stream>>>(dWhh0, dWhh0, pkD0, 8);
  pack_w<<<dim3(6144), 256, 0, stream>>>(dWih1, dWhh1, pkD1, 16);
  pack_bias<<<2, 256, 0, stream>>>(ebih0, ebhh0, bE0);
  pack_bias<<<2, 256, 0, stream>>>(ebih1, ebhh1, bE1);
  pack_bias<<<2, 256, 0, stream>>>(dbih0, dbhh0, bD0);
  pack_bias<<<2, 256, 0, stream>>>(dbih1, dbhh1, bD1);
  pack_wx<<<18, 256, 0, stream>>>(eWih0, wxE);
  pack_wx<<<18, 256, 0, stream>>>(dWih0, wxD);

  // zero-init fp16 states (ping index 0)
  {
    int n4 = (int)(S16 / 16);
    zero_fill<<<(n4 + 255) / 256, 256, 0, stream>>>((float4*)h0h[0], n4);
    zero_fill<<<(n4 + 255) / 256, 256, 0, stream>>>((float4*)h1h[0], n4);
  }

  dim3 grid(2048), blk(512);
  int p0 = 0, p1 = 0;
  // encoder
  for (int t = 0; t < T_HIST; ++t) {
    gru_step<8, true><<<grid, blk, 0, stream>>>(pkE0, h0h[p0], nullptr,
                                                h0h[1 - p0], bE0, wxE,
                                                x_input + (size_t)t * 3, 150);
    p0 ^= 1;
    gru_step<16, false><<<grid, blk, 0, stream>>>(pkE1, h0h[p0], h1h[p1],
                                                  h1h[1 - p1], bE1, nullptr, nullptr, 0);
    p1 ^= 1;
  }
  // autoregressive decoder
  for (int t = 0; t < FUT; ++t) {
    const float* xp; int xs;
    if (t == 0) { xp = x_input + (size_t)49 * 3; xs = 150; }
    else        { xp = out + (size_t)(t - 1) * 3; xs = 90; }
    gru_step<8, true><<<grid, blk, 0, stream>>>(pkD0, h0h[p0], nullptr,
                                                h0h[1 - p0], bD0, wxD, xp, xs);
    p0 ^= 1;
    gru_step<16, false><<<grid, blk, 0, stream>>>(pkD1, h0h[p0], h1h[p1],
                                                  h1h[1 - p1], bD1, nullptr, nullptr, 0);
    p1 ^= 1;
    fc_kernel<<<8192, 256, 0, stream>>>(h1h[p1], fcW, fcb, out + (size_t)t * 3);
  }
}